// Round 1
// baseline (895.639 us; speedup 1.0000x reference)
//
#include <hip/hip_runtime.h>
#include <math.h>

// Problem constants
#define B      2048
#define N      100000
#define DD     64
#define HH     256
#define KK     20
#define SAMPLE 4096
#define CAP    1536
#define RB     64      // rows per workgroup in gemm kernels
#define NSLICE 32      // candidate slices for knn_gemm (100000 = 32*3125)
#define SLICE  3125

#define INF_F (__builtin_inff())

__device__ __forceinline__ float wsum64(float v) {
    #pragma unroll
    for (int o = 32; o > 0; o >>= 1) v += __shfl_xor(v, o, 64);
    return v;
}

// ---------------------------------------------------------------- prep ------
// xs[b*64+d] = z[b*66+d]; xnorm[b] = sum(x^2)
__global__ __launch_bounds__(64) void prep_kernel(const float* __restrict__ z,
                                                  float* __restrict__ xs,
                                                  float* __restrict__ xnorm) {
    int b = blockIdx.x, d = threadIdx.x;
    float v = z[b * 66 + d];
    xs[b * 64 + d] = v;
    float s = wsum64(v * v);
    if (d == 0) xnorm[b] = s;
}

// ---------------------------------------------------------------- mlp -------
// x_dot = relu([x, t] @ W1 + b1) @ W2 + b2   (8 rows per block)
__global__ __launch_bounds__(256) void mlp_kernel(const float* __restrict__ z,
                                                  const float* __restrict__ tp,
                                                  const float* __restrict__ W1,
                                                  const float* __restrict__ b1,
                                                  const float* __restrict__ W2,
                                                  const float* __restrict__ b2,
                                                  float* __restrict__ xdot) {
    __shared__ float sin_[8][65];
    __shared__ float shid[8][HH];
    int tid = threadIdx.x;
    int row0 = blockIdx.x * 8;
    float tval = tp[0];
    for (int idx = tid; idx < 8 * 64; idx += 256) {
        int r = idx >> 6, d = idx & 63;
        sin_[r][d] = z[(row0 + r) * 66 + d];
    }
    if (tid < 8) sin_[tid][64] = tval;
    __syncthreads();

    int h = tid;
    float acc[8];
    #pragma unroll
    for (int r = 0; r < 8; ++r) acc[r] = b1[h];
    for (int i = 0; i < 65; ++i) {
        float wv = W1[i * HH + h];
        #pragma unroll
        for (int r = 0; r < 8; ++r) acc[r] = fmaf(sin_[r][i], wv, acc[r]);
    }
    #pragma unroll
    for (int r = 0; r < 8; ++r) shid[r][h] = fmaxf(acc[r], 0.f);
    __syncthreads();

    int d = tid & 63, rb = tid >> 6;
    for (int rr = rb; rr < 8; rr += 4) {
        float a = b2[d];
        for (int hh2 = 0; hh2 < HH; ++hh2)
            a = fmaf(shid[rr][hh2], W2[hh2 * 64 + d], a);
        xdot[(size_t)(row0 + rr) * 64 + d] = a;
    }
}

// ----------------------------------------------------------- sample gemm ----
// exact sq distances to candidates [0, 4096), written densely
__global__ __launch_bounds__(256, 4) void sample_gemm(const float* __restrict__ data,
                                                      const float* __restrict__ xs,
                                                      const float* __restrict__ xnorm,
                                                      float* __restrict__ samp) {
    int tid = threadIdx.x;
    int row0 = blockIdx.x * RB;
    int j0 = blockIdx.y * 1024;
    for (int c = 0; c < 4; ++c) {
        int j = j0 + c * 256 + tid;
        float4 dreg[16];
        const float4* dp = reinterpret_cast<const float4*>(data + (size_t)j * 64);
        #pragma unroll
        for (int kb = 0; kb < 16; ++kb) dreg[kb] = dp[kb];
        float dn = 0.f;
        #pragma unroll
        for (int kb = 0; kb < 16; ++kb)
            dn += dreg[kb].x * dreg[kb].x + dreg[kb].y * dreg[kb].y +
                  dreg[kb].z * dreg[kb].z + dreg[kb].w * dreg[kb].w;
        for (int r = 0; r < RB; ++r) {
            int row = row0 + r;
            const float4* xr = reinterpret_cast<const float4*>(xs + row * 64);
            float ax = 0.f, ay = 0.f, az = 0.f, aw = 0.f;
            #pragma unroll
            for (int kb = 0; kb < 16; ++kb) {
                float4 xv = xr[kb];
                ax = fmaf(xv.x, dreg[kb].x, ax);
                ay = fmaf(xv.y, dreg[kb].y, ay);
                az = fmaf(xv.z, dreg[kb].z, az);
                aw = fmaf(xv.w, dreg[kb].w, aw);
            }
            float dot = (ax + ay) + (az + aw);
            float sq = xnorm[row] + dn - 2.0f * dot;
            samp[(size_t)row * SAMPLE + j] = sq;
        }
    }
}

// ------------------------------------------------------------ thr select ----
// thr[row] = 20th smallest of the 4096 sampled sq values  (>= true 20th of N)
__global__ __launch_bounds__(64) void thr_select(const float* __restrict__ samp,
                                                 float* __restrict__ thr) {
    __shared__ float s[SAMPLE];
    int row = blockIdx.x, lane = threadIdx.x;
    for (int i = lane; i < SAMPLE; i += 64) s[i] = samp[(size_t)row * SAMPLE + i];
    __syncthreads();
    float last = INF_F;
    for (int k = 0; k < KK; ++k) {
        float v = INF_F; int p = -1;
        for (int i = lane; i < SAMPLE; i += 64) {
            float x = s[i];
            if (x < v) { v = x; p = i; }
        }
        #pragma unroll
        for (int o = 32; o > 0; o >>= 1) {
            float ov = __shfl_xor(v, o, 64);
            int op = __shfl_xor(p, o, 64);
            if (ov < v || (ov == v && op >= 0 && (p < 0 || op < p))) { v = ov; p = op; }
        }
        last = v;
        if (lane == 0 && p >= 0) s[p] = INF_F;
        __syncthreads();
    }
    if (lane == 0) thr[row] = last;
}

// -------------------------------------------------------------- knn gemm ----
// full scan: push (sq, j) with sq <= thr[row] into per-row buffers
__global__ __launch_bounds__(256, 4) void knn_gemm(const float* __restrict__ data,
                                                   const float* __restrict__ xs,
                                                   const float* __restrict__ xnorm,
                                                   const float* __restrict__ thr,
                                                   int* __restrict__ cnt,
                                                   float* __restrict__ bufd,
                                                   int* __restrict__ bufi) {
    int tid = threadIdx.x;
    int row0 = blockIdx.x * RB;
    int j0 = blockIdx.y * SLICE;
    for (int c = 0; c < 13; ++c) {
        int jj = c * 256 + tid;
        bool valid = jj < SLICE;
        int j = j0 + jj;
        float4 dreg[16];
        float dn;
        if (valid) {
            const float4* dp = reinterpret_cast<const float4*>(data + (size_t)j * 64);
            #pragma unroll
            for (int kb = 0; kb < 16; ++kb) dreg[kb] = dp[kb];
            dn = 0.f;
            #pragma unroll
            for (int kb = 0; kb < 16; ++kb)
                dn += dreg[kb].x * dreg[kb].x + dreg[kb].y * dreg[kb].y +
                      dreg[kb].z * dreg[kb].z + dreg[kb].w * dreg[kb].w;
        } else {
            #pragma unroll
            for (int kb = 0; kb < 16; ++kb) dreg[kb] = make_float4(0.f, 0.f, 0.f, 0.f);
            dn = INF_F;
        }
        for (int r = 0; r < RB; ++r) {
            int row = row0 + r;
            const float4* xr = reinterpret_cast<const float4*>(xs + row * 64);
            float ax = 0.f, ay = 0.f, az = 0.f, aw = 0.f;
            #pragma unroll
            for (int kb = 0; kb < 16; ++kb) {
                float4 xv = xr[kb];
                ax = fmaf(xv.x, dreg[kb].x, ax);
                ay = fmaf(xv.y, dreg[kb].y, ay);
                az = fmaf(xv.z, dreg[kb].z, az);
                aw = fmaf(xv.w, dreg[kb].w, aw);
            }
            float dot = (ax + ay) + (az + aw);
            float sq = xnorm[row] + dn - 2.0f * dot;
            if (sq <= thr[row]) {
                int pos = atomicAdd(&cnt[row], 1);
                if (pos < CAP) {
                    bufd[(size_t)row * CAP + pos] = sq;
                    bufi[(size_t)row * CAP + pos] = j;
                }
            }
        }
    }
}

// --------------------------------------------------------- select + finish --
__global__ __launch_bounds__(64) void select_finish(const float* __restrict__ bufd,
                                                    const int* __restrict__ bufi,
                                                    const int* __restrict__ cnt,
                                                    const float* __restrict__ xdot,
                                                    const float* __restrict__ vel,
                                                    float* __restrict__ out) {
    __shared__ float sd[CAP];
    __shared__ int   si[CAP];
    __shared__ float seld[KK];
    __shared__ int   seli[KK];
    __shared__ float selw[KK];
    int row = blockIdx.x, lane = threadIdx.x;
    int n = cnt[row];
    if (n > CAP) n = CAP;
    for (int i = lane; i < n; i += 64) {
        sd[i] = bufd[(size_t)row * CAP + i];
        si[i] = bufi[(size_t)row * CAP + i];
    }
    __syncthreads();
    // extract 20 smallest (tie-break: smaller candidate index, like lax.top_k)
    for (int k = 0; k < KK; ++k) {
        float v = INF_F; int id = 0x7fffffff; int p = -1;
        for (int i = lane; i < n; i += 64) {
            float x = sd[i]; int xi = si[i];
            if (x < v || (x == v && xi < id)) { v = x; id = xi; p = i; }
        }
        #pragma unroll
        for (int o = 32; o > 0; o >>= 1) {
            float ov = __shfl_xor(v, o, 64);
            int oid = __shfl_xor(id, o, 64);
            int op  = __shfl_xor(p, o, 64);
            if (ov < v || (ov == v && oid < id)) { v = ov; id = oid; p = op; }
        }
        if (lane == 0) {
            seld[k] = v; seli[k] = id;
            if (p >= 0) sd[p] = INF_F;
        }
        __syncthreads();
    }
    // weights: w = exp(-d^2/(2 h^2)) / (sum + 1e-12), h = max(d_20, 1e-12)
    float d20 = sqrtf(fmaxf(seld[KK - 1], 1e-30f));
    float h = fmaxf(d20, 1e-12f);
    float wk = 0.f;
    if (lane < KK) {
        float dd = sqrtf(fmaxf(seld[lane], 1e-30f));
        wk = expf(-(dd * dd) / (2.f * h * h));
    }
    float tot = wsum64(wk) + 1e-12f;
    if (lane < KK) selw[lane] = wk / tot;
    __syncthreads();
    // u = sum_k w_k * velocity[idx_k]   (lane = dim)
    float u = 0.f;
    #pragma unroll
    for (int k = 0; k < KK; ++k)
        u = fmaf(selw[k], vel[(size_t)seli[k] * 64 + lane], u);
    float xd = xdot[(size_t)row * 64 + lane];
    float du  = wsum64(u * xd);
    float nu2 = wsum64(u * u);
    float nx2 = wsum64(xd * xd);
    float l2  = wsum64((u - xd) * (u - xd));
    float nu = fmaxf(sqrtf(nu2), 1e-8f);
    float nx = fmaxf(sqrtf(nx2), 1e-8f);
    out[(size_t)row * 66 + lane] = xd;
    if (lane == 0) {
        out[(size_t)row * 66 + 64] = 1.f - du / (nu * nx);
        out[(size_t)row * 66 + 65] = l2;
    }
}

// ---------------------------------------------------------------------------
extern "C" void kernel_launch(void* const* d_in, const int* in_sizes, int n_in,
                              void* d_out, int out_size, void* d_ws, size_t ws_size,
                              hipStream_t stream) {
    const float* t_   = (const float*)d_in[0];
    const float* z    = (const float*)d_in[1];
    const float* data = (const float*)d_in[2];
    const float* vel  = (const float*)d_in[3];
    const float* W1   = (const float*)d_in[4];
    const float* b1   = (const float*)d_in[5];
    const float* W2   = (const float*)d_in[6];
    const float* b2   = (const float*)d_in[7];
    float* out = (float*)d_out;

    // workspace layout (floats)
    float* xs    = (float*)d_ws;            // 2048*64
    float* xnorm = xs + B * DD;             // 2048
    float* xdot  = xnorm + B;               // 2048*64
    float* thr   = xdot + B * DD;           // 2048
    int*   cnt   = (int*)(thr + B);         // 2048
    float* samp  = (float*)(cnt + B);       // 2048*4096
    float* bufd  = samp + (size_t)B * SAMPLE;   // 2048*1536
    int*   bufi  = (int*)(bufd + (size_t)B * CAP);

    hipMemsetAsync(cnt, 0, B * sizeof(int), stream);
    prep_kernel<<<B, 64, 0, stream>>>(z, xs, xnorm);
    mlp_kernel<<<B / 8, 256, 0, stream>>>(z, t_, W1, b1, W2, b2, xdot);
    sample_gemm<<<dim3(B / RB, SAMPLE / 1024), 256, 0, stream>>>(data, xs, xnorm, samp);
    thr_select<<<B, 64, 0, stream>>>(samp, thr);
    knn_gemm<<<dim3(B / RB, NSLICE), 256, 0, stream>>>(data, xs, xnorm, thr, cnt, bufd, bufi);
    select_finish<<<B, 64, 0, stream>>>(bufd, bufi, cnt, xdot, vel, out);
}